// Round 9
// baseline (219.393 us; speedup 1.0000x reference)
//
#include <hip/hip_runtime.h>
#include <stdint.h>

#define DEVINL __device__ __forceinline__

typedef __bf16 bf16x8 __attribute__((ext_vector_type(8)));
typedef float f32x4 __attribute__((ext_vector_type(4)));
typedef float f32x16 __attribute__((ext_vector_type(16)));
typedef uint32_t u32x4 __attribute__((ext_vector_type(4)));

DEVINL uint16_t f2bf(float f) {
    uint32_t u = __builtin_bit_cast(uint32_t, f);
    uint32_t r = (u + 0x7FFFu + ((u >> 16) & 1u)) >> 16;
    return (uint16_t)r;
}

DEVINL bf16x8 ld8(const uint16_t* p) {
    u32x4 v = *(const u32x4*)p;
    return __builtin_bit_cast(bf16x8, v);
}

DEVINL void gload16(const void* g, void* l) {
    __builtin_amdgcn_global_load_lds(
        (const __attribute__((address_space(1))) uint32_t*)g,
        (__attribute__((address_space(3))) uint32_t*)l, 16, 0, 0);
}

DEVINL uint32_t cvtpk(float lo, float hi) {
    uint32_t r;
    asm("v_cvt_pk_bf16_f32 %0, %1, %2" : "=v"(r) : "v"(lo), "v"(hi));
    return r;
}

DEVINL float exp2_fast(float x) {
    float r;
    asm("v_exp_f32 %0, %1" : "=v"(r) : "v"(x));
    return r;
}

// ---------------- fused prep: cvt x -> bf16 ; transpose+cvt Wqkv, Wproj ----------------
DEVINL void transW_body(const float* __restrict__ W, uint16_t* __restrict__ WT,
                        int Nn, int n0, int k0, int tid, uint16_t* t) {
#pragma unroll
    for (int i = 0; i < 4; ++i) {
        int c = tid + i * 256;              // 1024 float4 chunks
        int kr = c >> 4, nc = c & 15;
        float4 v = *(const float4*)(W + (size_t)(k0 + kr) * Nn + n0 + nc * 4);
        t[(nc * 4 + 0) * 65 + kr] = f2bf(v.x);
        t[(nc * 4 + 1) * 65 + kr] = f2bf(v.y);
        t[(nc * 4 + 2) * 65 + kr] = f2bf(v.z);
        t[(nc * 4 + 3) * 65 + kr] = f2bf(v.w);
    }
    __syncthreads();
#pragma unroll
    for (int i = 0; i < 2; ++i) {
        int c = tid + i * 256;              // 512 chunks of 8 bf16
        int nr = c >> 3, kc = c & 7;
        union { uint16_t u[8]; u32x4 v; } o;
#pragma unroll
        for (int j = 0; j < 8; ++j) o.u[j] = t[nr * 65 + kc * 8 + j];
        *(u32x4*)(WT + (size_t)(n0 + nr) * 1024 + k0 + kc * 8) = o.v;
    }
}

__global__ void k_prep(const float* __restrict__ x, uint16_t* __restrict__ xb,
                       const float* __restrict__ Wqkv, uint16_t* __restrict__ wqkvT,
                       const float* __restrict__ Wproj, uint16_t* __restrict__ wprojT) {
    __shared__ uint16_t t[64 * 65];
    int bid = blockIdx.x;
    int tid = threadIdx.x;
    if (bid < 4096) {
        int i = bid * 256 + tid;            // 1048576 chunks of 8 floats
        const float4* src = (const float4*)x + (size_t)i * 2;
        float4 a = src[0], b = src[1];
        union { uint16_t u[8]; u32x4 v; } o;
        o.u[0] = f2bf(a.x); o.u[1] = f2bf(a.y); o.u[2] = f2bf(a.z); o.u[3] = f2bf(a.w);
        o.u[4] = f2bf(b.x); o.u[5] = f2bf(b.y); o.u[6] = f2bf(b.z); o.u[7] = f2bf(b.w);
        ((u32x4*)xb)[i] = o.v;
    } else if (bid < 4864) {
        int idx = bid - 4096;               // 48 x 16 tiles
        transW_body(Wqkv, wqkvT, 3072, (idx % 48) * 64, (idx / 48) * 64, tid, t);
    } else {
        int idx = bid - 4864;               // 16 x 16 tiles
        transW_body(Wproj, wprojT, 1024, (idx % 16) * 64, (idx / 16) * 64, tid, t);
    }
}

// ---------------- GEMM: [8192][1024] x BT[Nd][1024] ----------------
// MODE 0: QKV -> q(*0.125*log2e) [bh][n][64];
//   k MFMA-fragment order [bh][n>>6][dh>>3][n&63][8dh-elems] (scalar stores);
//   v MFMA-fragment order [bh][n>>5][(n&31)>>3][dh][8key-elems] (packed uint2 stores)
// MODE 1: proj -> out f32 [8192][1024] + bias
template <int MODE>
__global__ __launch_bounds__(256) void k_gemm(
    const uint16_t* __restrict__ A, const uint16_t* __restrict__ BT,
    const float* __restrict__ bias,
    uint16_t* __restrict__ qo, uint16_t* __restrict__ ko, uint16_t* __restrict__ vo,
    float* __restrict__ out) {
    __shared__ uint16_t a_lds[128 * 64];
    __shared__ uint16_t b_lds[128 * 64];
    int tid = threadIdx.x;
    int w = tid >> 6, l = tid & 63;
    int l15 = l & 15, l4 = l >> 4;
    int m0 = blockIdx.y * 128, n0 = blockIdx.x * 128;
    int wr = w >> 1, wc = w & 1;
    f32x4 acc[4][4] = {};

    for (int kt = 0; kt < 16; ++kt) {
#pragma unroll
        for (int i = 0; i < 4; ++i) {
            int c = i * 256 + w * 64 + l;
            int row = c >> 3, slot = c & 7;
            int kc = slot ^ (row & 7);
            gload16(A + (size_t)(m0 + row) * 1024 + kt * 64 + kc * 8,
                    a_lds + (size_t)(i * 256 + w * 64) * 8);
            gload16(BT + (size_t)(n0 + row) * 1024 + kt * 64 + kc * 8,
                    b_lds + (size_t)(i * 256 + w * 64) * 8);
        }
        __syncthreads();
#pragma unroll
        for (int kkk = 0; kkk < 2; ++kkk) {
            bf16x8 af[4], bfr[4];
#pragma unroll
            for (int i = 0; i < 4; ++i) {
                int row = wr * 64 + i * 16 + l15;
                af[i] = ld8(a_lds + row * 64 + ((kkk * 4 + l4) ^ (row & 7)) * 8);
                int rowb = wc * 64 + i * 16 + l15;
                bfr[i] = ld8(b_lds + rowb * 64 + ((kkk * 4 + l4) ^ (rowb & 7)) * 8);
            }
#pragma unroll
            for (int i = 0; i < 4; ++i)
#pragma unroll
                for (int j = 0; j < 4; ++j)
                    acc[i][j] = __builtin_amdgcn_mfma_f32_16x16x32_bf16(
                        af[i], bfr[j], acc[i][j], 0, 0, 0);
        }
        __syncthreads();
    }

    if constexpr (MODE == 0) {
#pragma unroll
        for (int i = 0; i < 4; ++i)
#pragma unroll
            for (int j = 0; j < 4; ++j) {
                int d = n0 + wc * 64 + j * 16 + l15;
                int s = d >> 10, h = (d >> 6) & 15, dh = d & 63;
                // q pre-scaled by Dh^-0.5 * log2(e) so softmax runs in exp2 domain
                float sc = (s == 0) ? 0.18033688011112042f : 1.0f;
                if (s == 2) {
                    // v fragment-order, 4 consecutive keys pack into one uint2
                    int m = m0 + wr * 64 + i * 16 + l4 * 4;
                    int b = m >> 11, n = m & 2047;
                    int bh = b * 16 + h;
                    union { uint16_t u[4]; uint2 v2; } pk;
#pragma unroll
                    for (int r = 0; r < 4; ++r) pk.u[r] = f2bf(acc[i][j][r]);
                    size_t addr = (size_t)bh * 131072 + (size_t)(n >> 5) * 2048 +
                                  ((n & 31) >> 3) * 512 + dh * 8 + (n & 7);
                    *(uint2*)(vo + addr) = pk.v2;
                } else {
#pragma unroll
                    for (int r = 0; r < 4; ++r) {
                        int m = m0 + wr * 64 + i * 16 + l4 * 4 + r;
                        int b = m >> 11, n = m & 2047;
                        int bh = b * 16 + h;
                        uint16_t val = f2bf(acc[i][j][r] * sc);
                        if (s == 1) {
                            ko[(size_t)bh * 131072 + (size_t)(n >> 6) * 4096 +
                               (dh >> 3) * 512 + (n & 63) * 8 + (dh & 7)] = val;
                        } else {
                            qo[((size_t)bh * 2048 + n) * 64 + dh] = val;
                        }
                    }
                }
            }
    } else {
#pragma unroll
        for (int j = 0; j < 4; ++j) {
            int d = n0 + wc * 64 + j * 16 + l15;
            float bv = bias[d];
#pragma unroll
            for (int i = 0; i < 4; ++i)
#pragma unroll
                for (int r = 0; r < 4; ++r) {
                    int m = m0 + wr * 64 + i * 16 + l4 * 4 + r;
                    out[(size_t)m * 1024 + d] = acc[i][j][r] + bv;
                }
        }
    }
}

// ---------------- flash attention: zero LDS, zero barriers, K+V in registers ----------------
// q: [bh][2048][64] (pre-scaled, exp2 domain); kf_/vf_: fragment-ordered K/V.
// 32-key tiles (64 total). Per iter: QK (4 MFMA) -> loadK(t+1) ->
// {exp2 -> pack -> 2 PV MFMA} x2 -> loadV(t+1). Single-buffered regs (loads
// issued after last read = WAR-safe in-order). No shared state -> no barriers;
// waves free-run with staggered start tile (w*16) so MFMA/VALU phases of
// co-resident waves interleave (no-max softmax sums are order-invariant).
__global__ __launch_bounds__(256) void k_attn(
    const uint16_t* __restrict__ q, const uint16_t* __restrict__ kf_,
    const uint16_t* __restrict__ vf_, uint16_t* __restrict__ o) {
    int tid = threadIdx.x;
    int w = tid >> 6, l = tid & 63;
    int l31 = l & 31, g = l >> 5;
    int bid = blockIdx.x;
    int slot = bid >> 3;
    int bh = (bid & 7) * 8 + (slot >> 4);
    int qt = slot & 15;
    int qrow = qt * 128 + w * 32 + l31;
    const uint16_t* qb = q + ((size_t)bh * 2048 + qrow) * 64;
    // per-lane fragment bases
    const uint16_t* kfb = kf_ + (size_t)bh * 131072 + g * 512 + l31 * 8;
    const uint16_t* vfb = vf_ + (size_t)bh * 131072 + g * 512 + l31 * 8;

    bf16x8 qf[4];
#pragma unroll
    for (int kv = 0; kv < 4; ++kv) qf[kv] = ld8(qb + kv * 16 + g * 8);

    bf16x8 kr[4];   // K fragments of current tile (dh-slices kv=0..3)
    bf16x8 vr[4];   // V^T fragments: vr[dt*2+kv2]
    f32x16 oa[2] = {};
    float lsum = 0.f;

    auto loadK = [&](int t) {
        const uint16_t* p = kfb + (t >> 1) * 4096 + (t & 1) * 256;
        kr[0] = ld8(p);        kr[1] = ld8(p + 1024);
        kr[2] = ld8(p + 2048); kr[3] = ld8(p + 3072);
    };
    auto loadV = [&](int t) {
        const uint16_t* p = vfb + t * 2048;
        vr[0] = ld8(p);        vr[1] = ld8(p + 1024);   // dt=0: kv2=0,1
        vr[2] = ld8(p + 256);  vr[3] = ld8(p + 1280);   // dt=1: kv2=0,1
    };

    int start = w * 16;   // stagger waves across the 64 tiles
    loadK(start);
    loadV(start);
    int t = start;

    for (int it = 0; it < 64; ++it) {
        int tn = (t + 1) & 63;

        // S^T = K * Q^T (32 keys x 32 q)
        f32x16 stj = {};
        __builtin_amdgcn_s_setprio(1);
#pragma unroll
        for (int kv = 0; kv < 4; ++kv)
            stj = __builtin_amdgcn_mfma_f32_32x32x16_bf16(kr[kv], qf[kv], stj, 0, 0, 0);
        __builtin_amdgcn_s_setprio(0);
        loadK(tn);   // kr last read above; in-order issue -> WAR-safe

        // P = exp2(S), pack, PV interleaved per 16-key half
#pragma unroll
        for (int h = 0; h < 2; ++h) {
            float e[8];
#pragma unroll
            for (int jj = 0; jj < 8; ++jj) e[jj] = exp2_fast(stj[h * 8 + jj]);
            lsum += ((e[0] + e[1]) + (e[2] + e[3])) + ((e[4] + e[5]) + (e[6] + e[7]));
            uint32_t a0 = cvtpk(e[0], e[1]), a1 = cvtpk(e[2], e[3]);
            uint32_t b0 = cvtpk(e[4], e[5]), b1 = cvtpk(e[6], e[7]);
            auto r0 = __builtin_amdgcn_permlane32_swap(a0, b0, false, false);
            auto r1 = __builtin_amdgcn_permlane32_swap(a1, b1, false, false);
            u32x4 f;
            f[0] = r0[0]; f[1] = r1[0]; f[2] = r0[1]; f[3] = r1[1];
            bf16x8 pf = __builtin_bit_cast(bf16x8, f);
            __builtin_amdgcn_s_setprio(1);
            oa[0] = __builtin_amdgcn_mfma_f32_32x32x16_bf16(vr[h],     pf, oa[0], 0, 0, 0);
            oa[1] = __builtin_amdgcn_mfma_f32_32x32x16_bf16(vr[2 + h], pf, oa[1], 0, 0, 0);
            __builtin_amdgcn_s_setprio(0);
        }
        loadV(tn);   // vr last read above
        t = tn;
    }

    float ltot = lsum + __shfl_xor(lsum, 32, 64);
    float inv = 1.0f / ltot;
    int b = bh >> 4, h = bh & 15;
    uint16_t* ob = o + ((size_t)(b * 2048 + qrow)) * 1024 + h * 64;
#pragma unroll
    for (int dt = 0; dt < 2; ++dt)
#pragma unroll
        for (int rq = 0; rq < 4; ++rq) {
            union { uint16_t u[4]; uint2 v; } pk;
#pragma unroll
            for (int rr = 0; rr < 4; ++rr) pk.u[rr] = f2bf(oa[dt][rq * 4 + rr] * inv);
            int dh0 = dt * 32 + rq * 8 + g * 4;
            *(uint2*)(ob + dh0) = pk.v;
        }
}

extern "C" void kernel_launch(void* const* d_in, const int* in_sizes, int n_in,
                              void* d_out, int out_size, void* d_ws, size_t ws_size,
                              hipStream_t stream) {
    const float* x     = (const float*)d_in[0];
    // d_in[1] = xpos : unused by the reference
    const float* Wqkv  = (const float*)d_in[2];
    const float* Wproj = (const float*)d_in[3];
    const float* bproj = (const float*)d_in[4];
    float* out = (float*)d_out;

    char* ws = (char*)d_ws;
    uint16_t* xb     = (uint16_t*)(ws);                         // 16.78 MB
    uint16_t* wqkvT  = (uint16_t*)(ws + 16777216);              //  6.29 MB
    uint16_t* wprojT = (uint16_t*)(ws + 23068672);              //  2.10 MB
    uint16_t* qws    = (uint16_t*)(ws + 25165824);              // 16.78 MB
    uint16_t* kws    = (uint16_t*)(ws + 41943040);              // 16.78 MB (K fragment order)
    uint16_t* vfr    = (uint16_t*)(ws + 58720256);              // 16.78 MB (V fragment order)
    uint16_t* attnout = xb;  // xb is dead after QKV GEMM

    k_prep<<<dim3(5120), dim3(256), 0, stream>>>(x, xb, Wqkv, wqkvT, Wproj, wprojT);
    k_gemm<0><<<dim3(24, 64), dim3(256), 0, stream>>>(xb, wqkvT, nullptr, qws, kws, vfr, nullptr);
    k_attn<<<dim3(1024), dim3(256), 0, stream>>>(qws, kws, vfr, attnout);
    k_gemm<1><<<dim3(8, 64), dim3(256), 0, stream>>>(attnout, wprojT, bproj, nullptr, nullptr, nullptr, out);
}

// Round 10
// 209.209 us; speedup vs baseline: 1.0487x; 1.0487x over previous
//
#include <hip/hip_runtime.h>
#include <stdint.h>

#define DEVINL __device__ __forceinline__

typedef __bf16 bf16x8 __attribute__((ext_vector_type(8)));
typedef float f32x4 __attribute__((ext_vector_type(4)));
typedef float f32x16 __attribute__((ext_vector_type(16)));
typedef uint32_t u32x4 __attribute__((ext_vector_type(4)));

DEVINL uint16_t f2bf(float f) {
    uint32_t u = __builtin_bit_cast(uint32_t, f);
    uint32_t r = (u + 0x7FFFu + ((u >> 16) & 1u)) >> 16;
    return (uint16_t)r;
}

DEVINL bf16x8 ld8(const uint16_t* p) {
    u32x4 v = *(const u32x4*)p;
    return __builtin_bit_cast(bf16x8, v);
}

DEVINL void gload16(const void* g, void* l) {
    __builtin_amdgcn_global_load_lds(
        (const __attribute__((address_space(1))) uint32_t*)g,
        (__attribute__((address_space(3))) uint32_t*)l, 16, 0, 0);
}

DEVINL uint32_t cvtpk(float lo, float hi) {
    uint32_t r;
    asm("v_cvt_pk_bf16_f32 %0, %1, %2" : "=v"(r) : "v"(lo), "v"(hi));
    return r;
}

DEVINL float exp2_fast(float x) {
    float r;
    asm("v_exp_f32 %0, %1" : "=v"(r) : "v"(x));
    return r;
}

// ---------------- fused prep: cvt x -> bf16 ; transpose+cvt Wqkv, Wproj ----------------
DEVINL void transW_body(const float* __restrict__ W, uint16_t* __restrict__ WT,
                        int Nn, int n0, int k0, int tid, uint16_t* t) {
#pragma unroll
    for (int i = 0; i < 4; ++i) {
        int c = tid + i * 256;              // 1024 float4 chunks
        int kr = c >> 4, nc = c & 15;
        float4 v = *(const float4*)(W + (size_t)(k0 + kr) * Nn + n0 + nc * 4);
        t[(nc * 4 + 0) * 65 + kr] = f2bf(v.x);
        t[(nc * 4 + 1) * 65 + kr] = f2bf(v.y);
        t[(nc * 4 + 2) * 65 + kr] = f2bf(v.z);
        t[(nc * 4 + 3) * 65 + kr] = f2bf(v.w);
    }
    __syncthreads();
#pragma unroll
    for (int i = 0; i < 2; ++i) {
        int c = tid + i * 256;              // 512 chunks of 8 bf16
        int nr = c >> 3, kc = c & 7;
        union { uint16_t u[8]; u32x4 v; } o;
#pragma unroll
        for (int j = 0; j < 8; ++j) o.u[j] = t[nr * 65 + kc * 8 + j];
        *(u32x4*)(WT + (size_t)(n0 + nr) * 1024 + k0 + kc * 8) = o.v;
    }
}

__global__ void k_prep(const float* __restrict__ x, uint16_t* __restrict__ xb,
                       const float* __restrict__ Wqkv, uint16_t* __restrict__ wqkvT,
                       const float* __restrict__ Wproj, uint16_t* __restrict__ wprojT) {
    __shared__ uint16_t t[64 * 65];
    int bid = blockIdx.x;
    int tid = threadIdx.x;
    if (bid < 4096) {
        int i = bid * 256 + tid;            // 1048576 chunks of 8 floats
        const float4* src = (const float4*)x + (size_t)i * 2;
        float4 a = src[0], b = src[1];
        union { uint16_t u[8]; u32x4 v; } o;
        o.u[0] = f2bf(a.x); o.u[1] = f2bf(a.y); o.u[2] = f2bf(a.z); o.u[3] = f2bf(a.w);
        o.u[4] = f2bf(b.x); o.u[5] = f2bf(b.y); o.u[6] = f2bf(b.z); o.u[7] = f2bf(b.w);
        ((u32x4*)xb)[i] = o.v;
    } else if (bid < 4864) {
        int idx = bid - 4096;               // 48 x 16 tiles
        transW_body(Wqkv, wqkvT, 3072, (idx % 48) * 64, (idx / 48) * 64, tid, t);
    } else {
        int idx = bid - 4864;               // 16 x 16 tiles
        transW_body(Wproj, wprojT, 1024, (idx % 16) * 64, (idx / 16) * 64, tid, t);
    }
}

// ------------- transpose v: bf16 [bh][2048][64] -> [bh][64][2048] -------------
__global__ void k_transV(const uint16_t* __restrict__ vn, uint16_t* __restrict__ vt) {
    __shared__ uint16_t t[64 * 65];
    int bh = blockIdx.y;
    int n0 = blockIdx.x * 64;
    int tid = threadIdx.x;
#pragma unroll
    for (int i = 0; i < 2; ++i) {
        int c = tid + i * 256;              // 512 chunks of 8
        int n = c >> 3, dc = c & 7;
        u32x4 vv = *(const u32x4*)(vn + ((size_t)bh * 2048 + n0 + n) * 64 + dc * 8);
        union { u32x4 v4; uint16_t u[8]; } in; in.v4 = vv;
#pragma unroll
        for (int j = 0; j < 8; ++j) t[(dc * 8 + j) * 65 + n] = in.u[j];
    }
    __syncthreads();
#pragma unroll
    for (int i = 0; i < 2; ++i) {
        int c = tid + i * 256;
        int dh = c >> 3, nc = c & 7;
        union { uint16_t u[8]; u32x4 v4; } o;
#pragma unroll
        for (int j = 0; j < 8; ++j) o.u[j] = t[dh * 65 + nc * 8 + j];
        *(u32x4*)(vt + ((size_t)bh * 64 + dh) * 2048 + n0 + nc * 8) = o.v4;
    }
}

// ---------------- GEMM: [8192][1024] x BT[Nd][1024] ----------------
// XCD-panel-blocked 1D grid: xcd = bid&7 owns M-tiles [xcd*8, xcd*8+8);
// within an XCD blocks walk B-panel-major (8 consecutive blocks share one
// B-panel, 8 A-panels) so A-chunk (2MB) + active B-panels stay L2-resident.
// NT = number of N-tiles (grid = 64*NT blocks, 8*8*NT decode, NT*8%...).
// MODE 0: QKV -> scatter q(*0.125*log2e)/k/v as bf16 into [bh][n][64] layouts
// MODE 1: proj -> out f32 [8192][1024] + bias
template <int MODE, int NT>
__global__ __launch_bounds__(256) void k_gemm(
    const uint16_t* __restrict__ A, const uint16_t* __restrict__ BT,
    const float* __restrict__ bias,
    uint16_t* __restrict__ qo, uint16_t* __restrict__ ko, uint16_t* __restrict__ vo,
    float* __restrict__ out) {
    __shared__ uint16_t a_lds[128 * 64];
    __shared__ uint16_t b_lds[128 * 64];
    int tid = threadIdx.x;
    int w = tid >> 6, l = tid & 63;
    int l15 = l & 15, l4 = l >> 4;
    int bid = blockIdx.x;
    int mt = ((bid & 7) << 3) + ((bid >> 3) & 7);   // xcd*8 + local M index
    int nt = bid >> 6;                               // B-panel index
    int m0 = mt * 128, n0 = nt * 128;
    int wr = w >> 1, wc = w & 1;
    f32x4 acc[4][4] = {};

    for (int kt = 0; kt < 16; ++kt) {
#pragma unroll
        for (int i = 0; i < 4; ++i) {
            int c = i * 256 + w * 64 + l;
            int row = c >> 3, slot = c & 7;
            int kc = slot ^ (row & 7);
            gload16(A + (size_t)(m0 + row) * 1024 + kt * 64 + kc * 8,
                    a_lds + (size_t)(i * 256 + w * 64) * 8);
            gload16(BT + (size_t)(n0 + row) * 1024 + kt * 64 + kc * 8,
                    b_lds + (size_t)(i * 256 + w * 64) * 8);
        }
        __syncthreads();
#pragma unroll
        for (int kkk = 0; kkk < 2; ++kkk) {
            bf16x8 af[4], bfr[4];
#pragma unroll
            for (int i = 0; i < 4; ++i) {
                int row = wr * 64 + i * 16 + l15;
                af[i] = ld8(a_lds + row * 64 + ((kkk * 4 + l4) ^ (row & 7)) * 8);
                int rowb = wc * 64 + i * 16 + l15;
                bfr[i] = ld8(b_lds + rowb * 64 + ((kkk * 4 + l4) ^ (rowb & 7)) * 8);
            }
#pragma unroll
            for (int i = 0; i < 4; ++i)
#pragma unroll
                for (int j = 0; j < 4; ++j)
                    acc[i][j] = __builtin_amdgcn_mfma_f32_16x16x32_bf16(
                        af[i], bfr[j], acc[i][j], 0, 0, 0);
        }
        __syncthreads();
    }

    if constexpr (MODE == 0) {
#pragma unroll
        for (int i = 0; i < 4; ++i)
#pragma unroll
            for (int j = 0; j < 4; ++j) {
                int d = n0 + wc * 64 + j * 16 + l15;
                int s = d >> 10, h = (d >> 6) & 15, dh = d & 63;
                uint16_t* dst0 = (s == 0) ? qo : (s == 1) ? ko : vo;
                // q pre-scaled by Dh^-0.5 * log2(e) so softmax runs in exp2 domain
                float sc = (s == 0) ? 0.18033688011112042f : 1.0f;
#pragma unroll
                for (int r = 0; r < 4; ++r) {
                    int m = m0 + wr * 64 + i * 16 + l4 * 4 + r;
                    int b = m >> 11, n = m & 2047;
                    dst0[((size_t)(b * 16 + h) * 2048 + n) * 64 + dh] = f2bf(acc[i][j][r] * sc);
                }
            }
    } else {
#pragma unroll
        for (int j = 0; j < 4; ++j) {
            int d = n0 + wc * 64 + j * 16 + l15;
            float bv = bias[d];
#pragma unroll
            for (int i = 0; i < 4; ++i)
#pragma unroll
                for (int r = 0; r < 4; ++r) {
                    int m = m0 + wr * 64 + i * 16 + l4 * 4 + r;
                    out[(size_t)m * 1024 + d] = acc[i][j][r] + bv;
                }
        }
    }
}

// ---------------- flash attention (no-max softmax, exp2 domain) ----------------
// R7-proven body (103.6 us): split-barrier counted-vmcnt pipeline, K/V in LDS,
// scalar lsum, XCD swizzle (16 q-tile blocks of one bh per XCD).
__global__ __launch_bounds__(256) void k_attn(
    const uint16_t* __restrict__ q, const uint16_t* __restrict__ kk_,
    const uint16_t* __restrict__ vt, uint16_t* __restrict__ o) {
    __shared__ uint16_t k_lds[2][64 * 64];
    __shared__ uint16_t v_lds[2][64 * 64];
    int tid = threadIdx.x;
    int w = tid >> 6, l = tid & 63;
    int l31 = l & 31, g = l >> 5;
    int bid = blockIdx.x;
    int slot = bid >> 3;
    int bh = (bid & 7) * 8 + (slot >> 4);
    int qt = slot & 15;
    int qrow = qt * 128 + w * 32 + l31;
    const uint16_t* qb = q + ((size_t)bh * 2048 + qrow) * 64;
    const uint16_t* kbase = kk_ + (size_t)bh * 2048 * 64;
    const uint16_t* vbase = vt + (size_t)bh * 64 * 2048;

    bf16x8 qf[4];
#pragma unroll
    for (int kv = 0; kv < 4; ++kv) qf[kv] = ld8(qb + kv * 16 + g * 8);

    // staging source pointers (lane-fixed, advanced by constants each tile)
    int c0 = w * 128 + l;
    int rr0 = c0 >> 3, sl0 = c0 & 7;
    int kc0 = sl0 ^ (rr0 & 7);
    int rr1 = rr0 + 8, kc1 = sl0 ^ (rr1 & 7);
    const uint16_t* kp0 = kbase + rr0 * 64 + kc0 * 8;
    const uint16_t* kp1 = kbase + rr1 * 64 + kc1 * 8;
    const uint16_t* vp0 = vbase + (size_t)rr0 * 2048 + kc0 * 8;
    const uint16_t* vp1 = vbase + (size_t)rr1 * 2048 + kc1 * 8;
    uint16_t* kd0 = k_lds[0] + w * 1024;
    uint16_t* kd1 = k_lds[1] + w * 1024;
    uint16_t* vd0 = v_lds[0] + w * 1024;
    uint16_t* vd1 = v_lds[1] + w * 1024;

    f32x16 oa[2] = {};
    float lsum = 0.f;

    auto stage = [&](uint16_t* kd, uint16_t* vd) {
        gload16(kp0, kd);       gload16(kp1, kd + 512);   // K first,
        gload16(vp0, vd);       gload16(vp1, vd + 512);   // V second (vmcnt order)
        kp0 += 4096; kp1 += 4096; vp0 += 64; vp1 += 64;
    };

    stage(kd0, vd0);   // tile 0 -> buf 0  (4 outstanding)

    auto body = [&](int t, const uint16_t* kb, const uint16_t* vb,
                    uint16_t* kdn, uint16_t* vdn) {
        // K(t) ready for all waves
        asm volatile("s_waitcnt vmcnt(2)\n\ts_barrier" ::: "memory");
        if (t < 31) stage(kdn, vdn);   // issue next tile ASAP (lands during compute)

        // S^T = K * Q^T, then P = exp2(S) in-register (32 keys at a time)
        bf16x8 pfrag[4];
#pragma unroll
        for (int j = 0; j < 2; ++j) {
            int key = j * 32 + l31;
            f32x16 stj = {};
            __builtin_amdgcn_s_setprio(1);
#pragma unroll
            for (int kv = 0; kv < 4; ++kv) {
                bf16x8 kf = ld8(kb + key * 64 + ((2 * kv + g) ^ (key & 7)) * 8);
                stj = __builtin_amdgcn_mfma_f32_32x32x16_bf16(kf, qf[kv], stj, 0, 0, 0);
            }
            __builtin_amdgcn_s_setprio(0);
#pragma unroll
            for (int h = 0; h < 2; ++h) {
                float e[8];
#pragma unroll
                for (int jj = 0; jj < 8; ++jj) e[jj] = exp2_fast(stj[h * 8 + jj]);
                lsum += ((e[0] + e[1]) + (e[2] + e[3])) + ((e[4] + e[5]) + (e[6] + e[7]));
                uint32_t a0 = cvtpk(e[0], e[1]), a1 = cvtpk(e[2], e[3]);
                uint32_t b0 = cvtpk(e[4], e[5]), b1 = cvtpk(e[6], e[7]);
                auto r0 = __builtin_amdgcn_permlane32_swap(a0, b0, false, false);
                auto r1 = __builtin_amdgcn_permlane32_swap(a1, b1, false, false);
                u32x4 f;
                f[0] = r0[0]; f[1] = r1[0]; f[2] = r0[1]; f[3] = r1[1];
                pfrag[j * 2 + h] = __builtin_bit_cast(bf16x8, f);
            }
        }

        // V(t) ready for all waves
        if (t < 31) asm volatile("s_waitcnt vmcnt(4)\n\ts_barrier" ::: "memory");
        else        asm volatile("s_waitcnt vmcnt(0)\n\ts_barrier" ::: "memory");

        // O^T += V^T * P^T
        __builtin_amdgcn_s_setprio(1);
#pragma unroll
        for (int kv = 0; kv < 4; ++kv) {
#pragma unroll
            for (int dt = 0; dt < 2; ++dt) {
                int dh = dt * 32 + l31;
                bf16x8 vf = ld8(vb + dh * 64 + ((2 * kv + g) ^ (dh & 7)) * 8);
                oa[dt] = __builtin_amdgcn_mfma_f32_32x32x16_bf16(vf, pfrag[kv], oa[dt], 0, 0, 0);
            }
        }
        __builtin_amdgcn_s_setprio(0);
    };

    for (int kt = 0; kt < 32; kt += 2) {
        body(kt,     k_lds[0], v_lds[0], kd1, vd1);
        body(kt + 1, k_lds[1], v_lds[1], kd0, vd0);
    }

    float ltot = lsum + __shfl_xor(lsum, 32, 64);
    float inv = 1.0f / ltot;
    int b = bh >> 4, h = bh & 15;
    uint16_t* ob = o + ((size_t)(b * 2048 + qrow)) * 1024 + h * 64;
#pragma unroll
    for (int dt = 0; dt < 2; ++dt)
#pragma unroll
        for (int rq = 0; rq < 4; ++rq) {
            union { uint16_t u[4]; uint2 v; } pk;
#pragma unroll
            for (int rr = 0; rr < 4; ++rr) pk.u[rr] = f2bf(oa[dt][rq * 4 + rr] * inv);
            int dh0 = dt * 32 + rq * 8 + g * 4;
            *(uint2*)(ob + dh0) = pk.v;
        }
}

extern "C" void kernel_launch(void* const* d_in, const int* in_sizes, int n_in,
                              void* d_out, int out_size, void* d_ws, size_t ws_size,
                              hipStream_t stream) {
    const float* x     = (const float*)d_in[0];
    // d_in[1] = xpos : unused by the reference
    const float* Wqkv  = (const float*)d_in[2];
    const float* Wproj = (const float*)d_in[3];
    const float* bproj = (const float*)d_in[4];
    float* out = (float*)d_out;

    char* ws = (char*)d_ws;
    uint16_t* xb     = (uint16_t*)(ws);                         // 16.78 MB
    uint16_t* wqkvT  = (uint16_t*)(ws + 16777216);              //  6.29 MB
    uint16_t* wprojT = (uint16_t*)(ws + 23068672);              //  2.10 MB
    uint16_t* qws    = (uint16_t*)(ws + 25165824);              // 16.78 MB
    uint16_t* kws    = (uint16_t*)(ws + 41943040);              // 16.78 MB
    uint16_t* vT     = (uint16_t*)(ws + 58720256);              // 16.78 MB
    uint16_t* vnat   = (uint16_t*)(ws + 75497472);              // 16.78 MB (total ~92.3 MB)
    uint16_t* attnout = xb;  // xb is dead after QKV GEMM

    k_prep<<<dim3(5120), dim3(256), 0, stream>>>(x, xb, Wqkv, wqkvT, Wproj, wprojT);
    k_gemm<0, 24><<<dim3(1536), dim3(256), 0, stream>>>(xb, wqkvT, nullptr, qws, kws, vnat, nullptr);
    k_transV<<<dim3(32, 64), dim3(256), 0, stream>>>(vnat, vT);
    k_attn<<<dim3(1024), dim3(256), 0, stream>>>(qws, kws, vT, attnout);
    k_gemm<1, 8><<<dim3(512), dim3(256), 0, stream>>>(attnout, wprojT, bproj, nullptr, nullptr, nullptr, out);
}